// Round 7
// baseline (523.502 us; speedup 1.0000x reference)
//
#include <hip/hip_runtime.h>

#define DEV __device__ __forceinline__

typedef __attribute__((ext_vector_type(8))) short bf16x8;
typedef __attribute__((ext_vector_type(4))) float f32x4;

DEV float bf2f(unsigned short u) { return __uint_as_float(((unsigned int)u) << 16); }
DEV unsigned short f2bf(float f) {
    unsigned int x = __float_as_uint(f);
    return (unsigned short)((x + 0x7fffu + ((x >> 16) & 1u)) >> 16);
}
DEV float gelu_exact(float x) { return 0.5f * x * (1.0f + erff(x * 0.7071067811865475f)); }

DEV void gload16(const void* g, void* l) {
    __builtin_amdgcn_global_load_lds((const __attribute__((address_space(1))) void*)g,
                                     (__attribute__((address_space(3))) void*)l, 16, 0, 0);
}

template <int OFF>
DEV bf16x8 ds_read128(unsigned addr) {
    bf16x8 r;
    asm volatile("ds_read_b128 %0, %1 offset:%2" : "=v"(r) : "v"(addr), "i"(OFF));
    return r;
}

// ---------------------------------------------------------------------------
// transpose + cast: w f32 [R][C] -> wT bf16 [C][R]
__global__ __launch_bounds__(256) void transpose_cast_w(const float* __restrict__ in,
                                                        unsigned short* __restrict__ out,
                                                        int R, int C) {
    __shared__ float tile[32][33];
    int c0 = blockIdx.x * 32, r0 = blockIdx.y * 32;
    int tx = threadIdx.x, ty = threadIdx.y;  // 32 x 8
#pragma unroll
    for (int i = 0; i < 32; i += 8)
        tile[ty + i][tx] = in[(size_t)(r0 + ty + i) * C + (c0 + tx)];
    __syncthreads();
#pragma unroll
    for (int i = 0; i < 32; i += 8)
        out[(size_t)(c0 + ty + i) * R + (r0 + tx)] = f2bf(tile[tx][ty + i]);
}

// f32 -> bf16 cast, 4 elems/thread
__global__ __launch_bounds__(256) void cast_f32_bf16(const float* __restrict__ in,
                                                     unsigned short* __restrict__ out, int n4) {
    int i = blockIdx.x * 256 + threadIdx.x;
    if (i >= n4) return;
    float4 v = ((const float4*)in)[i];
    unsigned short o[4] = {f2bf(v.x), f2bf(v.y), f2bf(v.z), f2bf(v.w)};
    *(uint2*)(out + (size_t)i * 4) = *(uint2*)o;
}

// ---------------------------------------------------------------------------
// 128x128 bf16 GEMM, BK=32, 4 waves (2x2), 3-buffer LDS pipeline (48 KiB),
// 3 blocks/CU, ONE barrier per K-tile, counted vmcnt(4) steady state.
//   C = act( scale * (A @ BT^T) + bias ),  A:[M][K] lda, BT:[N][K] ldb, bf16.
//   Per tile: vmcnt(4) | barrier | STAGE(t+2) | 8 ds_read | lgkm(0) | 16 MFMA.
//   Swizzle (BK=32, 64B rows): physical chunk = c ^ ((row>>1)&3); applied on
//   global source (LDS dest linear, rule 21) and on ds_read addresses.
//   XCD-aware block remap. BIAS_MODE: 0 none, 1 per-col, 2 per-row.

template <int BIAS_MODE, bool GELU_ACT, bool OUT_F32>
__global__ __launch_bounds__(256, 3) void gemm128(const unsigned short* __restrict__ A,
                                                  const unsigned short* __restrict__ BT,
                                                  const float* __restrict__ bias,
                                                  float* __restrict__ Cf,
                                                  unsigned short* __restrict__ Cb,
                                                  int N, int K, int lda, int ldb, float scale,
                                                  long sA, long sB, long sC, long sBias) {
    // XCD-aware bijective block remap (nwg % 8 == 0 for all our grids)
    const int gx = gridDim.x, gy = gridDim.y;
    int f = blockIdx.x + gx * (blockIdx.y + gy * blockIdx.z);
    const int nwg = gx * gy * gridDim.z;
    f = (f & 7) * (nwg >> 3) + (f >> 3);
    const int bz = f / (gx * gy);
    const int rem = f - bz * gx * gy;
    const int by = rem / gx;
    const int bx = rem - by * gx;

    A += (long)bz * sA;
    BT += (long)bz * sB;
    if (BIAS_MODE) bias += (long)bz * sBias;

    const int tid = threadIdx.x;
    const int lane = tid & 63;
    const int wave = tid >> 6;          // 0..3
    const int wr = wave >> 1;           // 0..1 : 64-row strip
    const int wc = wave & 1;            // 0..1 : 64-col strip
    const int llo = lane & 15, lhi = lane >> 4;
    const int bm = bx * 128, bn = by * 128;

    // 3 buffers x [A 8KB | B 8KB] = 48 KiB
    __shared__ unsigned char ldsraw[49152];
    char* ldsc = (char*)&ldsraw[0];

    // ds_read addresses: row*64B + swizzled-chunk*16B; swizzle bits depend only
    // on llo (row = strip + m*16 + llo; m*16 and strip don't touch (row>>1)&3)
    const unsigned swz = (unsigned)((lhi ^ ((llo >> 1) & 3)) * 16);
    const unsigned base0 = (unsigned)(size_t)&ldsraw[0];
    const unsigned aA = base0 + (unsigned)(wr * 64 + llo) * 64u + swz;
    const unsigned aB = base0 + 8192u + (unsigned)(wc * 64 + llo) * 64u + swz;

    // staging: thread covers slots d = L*256+tid (L=0,1) of 512 16B-chunks per
    // matrix: physical (row = d>>2, p = d&3) holds logical chunk p^((row>>1)&3).
    const unsigned short* pA[2];
    const unsigned short* pB[2];
#pragma unroll
    for (int L = 0; L < 2; ++L) {
        const int d = L * 256 + tid;
        const int r = d >> 2;
        const int sc = ((d & 3) ^ ((r >> 1) & 3)) * 8;
        pA[L] = A + (size_t)(bm + r) * lda + sc;
        pB[L] = BT + (size_t)(bn + r) * ldb + sc;
    }
    const unsigned stW = (unsigned)wave * 1024u;  // wave-uniform dest base part

#define STG(ktv, off)                                                        \
    {                                                                        \
        gload16(pA[0] + (ktv), ldsc + (off) + 0 * 4096 + stW);               \
        gload16(pA[1] + (ktv), ldsc + (off) + 1 * 4096 + stW);               \
        gload16(pB[0] + (ktv), ldsc + (off) + 8192 + 0 * 4096 + stW);        \
        gload16(pB[1] + (ktv), ldsc + (off) + 8192 + 1 * 4096 + stW);        \
    }

    f32x4 acc[4][4] = {};

#define VM4 asm volatile("s_waitcnt vmcnt(4)" :::)
#define VM0 asm volatile("s_waitcnt vmcnt(0)" :::)

#define TILE(WAIT, DO_STAGE, ktv)                                            \
    {                                                                        \
        WAIT;                                                                \
        __builtin_amdgcn_sched_barrier(0);                                   \
        __builtin_amdgcn_s_barrier();                                        \
        __builtin_amdgcn_sched_barrier(0);                                   \
        if (DO_STAGE) STG(ktv, off_s);                                       \
        const unsigned ar = aA + off_r, br = aB + off_r;                     \
        bf16x8 a0 = ds_read128<0>(ar);                                       \
        bf16x8 a1 = ds_read128<1024>(ar);                                    \
        bf16x8 a2 = ds_read128<2048>(ar);                                    \
        bf16x8 a3 = ds_read128<3072>(ar);                                    \
        bf16x8 b0 = ds_read128<0>(br);                                       \
        bf16x8 b1 = ds_read128<1024>(br);                                    \
        bf16x8 b2 = ds_read128<2048>(br);                                    \
        bf16x8 b3 = ds_read128<3072>(br);                                    \
        asm volatile("s_waitcnt lgkmcnt(0)" :::);                            \
        __builtin_amdgcn_sched_barrier(0);                                   \
        __builtin_amdgcn_s_setprio(1);                                       \
        acc[0][0] = __builtin_amdgcn_mfma_f32_16x16x32_bf16(a0, b0, acc[0][0], 0, 0, 0); \
        acc[0][1] = __builtin_amdgcn_mfma_f32_16x16x32_bf16(a0, b1, acc[0][1], 0, 0, 0); \
        acc[0][2] = __builtin_amdgcn_mfma_f32_16x16x32_bf16(a0, b2, acc[0][2], 0, 0, 0); \
        acc[0][3] = __builtin_amdgcn_mfma_f32_16x16x32_bf16(a0, b3, acc[0][3], 0, 0, 0); \
        acc[1][0] = __builtin_amdgcn_mfma_f32_16x16x32_bf16(a1, b0, acc[1][0], 0, 0, 0); \
        acc[1][1] = __builtin_amdgcn_mfma_f32_16x16x32_bf16(a1, b1, acc[1][1], 0, 0, 0); \
        acc[1][2] = __builtin_amdgcn_mfma_f32_16x16x32_bf16(a1, b2, acc[1][2], 0, 0, 0); \
        acc[1][3] = __builtin_amdgcn_mfma_f32_16x16x32_bf16(a1, b3, acc[1][3], 0, 0, 0); \
        acc[2][0] = __builtin_amdgcn_mfma_f32_16x16x32_bf16(a2, b0, acc[2][0], 0, 0, 0); \
        acc[2][1] = __builtin_amdgcn_mfma_f32_16x16x32_bf16(a2, b1, acc[2][1], 0, 0, 0); \
        acc[2][2] = __builtin_amdgcn_mfma_f32_16x16x32_bf16(a2, b2, acc[2][2], 0, 0, 0); \
        acc[2][3] = __builtin_amdgcn_mfma_f32_16x16x32_bf16(a2, b3, acc[2][3], 0, 0, 0); \
        acc[3][0] = __builtin_amdgcn_mfma_f32_16x16x32_bf16(a3, b0, acc[3][0], 0, 0, 0); \
        acc[3][1] = __builtin_amdgcn_mfma_f32_16x16x32_bf16(a3, b1, acc[3][1], 0, 0, 0); \
        acc[3][2] = __builtin_amdgcn_mfma_f32_16x16x32_bf16(a3, b2, acc[3][2], 0, 0, 0); \
        acc[3][3] = __builtin_amdgcn_mfma_f32_16x16x32_bf16(a3, b3, acc[3][3], 0, 0, 0); \
        __builtin_amdgcn_s_setprio(0);                                       \
        off_r = (off_r == 32768u) ? 0u : off_r + 16384u;                     \
        off_s = (off_s == 32768u) ? 0u : off_s + 16384u;                     \
    }

    const int nt = K >> 5;  // K-tiles of 32 (>= 4 for all our shapes)

    unsigned off_r = 0u, off_s = 32768u;
    // prologue: tile0 -> buf0, tile1 -> buf1 (8 loads in flight)
    STG(0, 0u);
    STG(32, 16384u);

    int ktv = 64;
    for (int t = 0; t < nt - 2; ++t) {
        TILE(VM4, true, ktv);   // stages tile t+2 into buf[(t+2)%3]
        ktv += 32;
    }
    TILE(VM4, false, 0);        // tile nt-2: retire its 4 loads, no stage
    TILE(VM0, false, 0);        // tile nt-1: drain remaining 4
#undef TILE
#undef STG
#undef VM4
#undef VM0

    // epilogue: C/D frag layout col = llo, row = lhi*4 + j
#pragma unroll
    for (int m = 0; m < 4; ++m) {
#pragma unroll
        for (int n = 0; n < 4; ++n) {
            const int col = bn + wc * 64 + n * 16 + llo;
            float bcol = 0.f;
            if constexpr (BIAS_MODE == 1) bcol = bias[col];
#pragma unroll
            for (int j = 0; j < 4; ++j) {
                const int row = bm + wr * 64 + m * 16 + lhi * 4 + j;
                float v = acc[m][n][j] * scale + bcol;
                if constexpr (BIAS_MODE == 2) v += bias[row];
                if constexpr (GELU_ACT) v = gelu_exact(v);
                const size_t idx = (size_t)bz * (size_t)sC + (size_t)row * N + col;
                if constexpr (OUT_F32) Cf[idx] = v;
                else Cb[idx] = f2bf(v);
            }
        }
    }
}

// ---------------------------------------------------------------------------
// row softmax in place on bf16 scores, one block per row, T = 8*blockDim.x
__global__ __launch_bounds__(256) void softmax_rows(unsigned short* __restrict__ s, int T) {
    __shared__ float red[4];
    unsigned short* p = s + (size_t)blockIdx.x * T;
    const int tid = threadIdx.x;

    uint4 raw = *(const uint4*)(p + tid * 8);
    const unsigned short* u = (const unsigned short*)&raw;
    float v[8];
#pragma unroll
    for (int j = 0; j < 8; ++j) v[j] = bf2f(u[j]);

    float mx = -3.4e38f;
#pragma unroll
    for (int j = 0; j < 8; ++j) mx = fmaxf(mx, v[j]);
#pragma unroll
    for (int o = 32; o; o >>= 1) mx = fmaxf(mx, __shfl_xor(mx, o));
    if ((tid & 63) == 0) red[tid >> 6] = mx;
    __syncthreads();
    mx = fmaxf(fmaxf(red[0], red[1]), fmaxf(red[2], red[3]));
    __syncthreads();

    float sum = 0.f;
#pragma unroll
    for (int j = 0; j < 8; ++j) {
        v[j] = expf(v[j] - mx);
        sum += v[j];
    }
#pragma unroll
    for (int o = 32; o; o >>= 1) sum += __shfl_xor(sum, o);
    if ((tid & 63) == 0) red[tid >> 6] = sum;
    __syncthreads();
    sum = red[0] + red[1] + red[2] + red[3];
    const float inv = 1.0f / sum;

    unsigned short o8[8];
#pragma unroll
    for (int j = 0; j < 8; ++j) o8[j] = f2bf(v[j] * inv);
    *(uint4*)(p + tid * 8) = *(uint4*)o8;
}

// ---------------------------------------------------------------------------
DEV float block_sum(float v, float* red, int tid) {
#pragma unroll
    for (int o = 32; o; o >>= 1) v += __shfl_xor(v, o);
    if ((tid & 63) == 0) red[tid >> 6] = v;
    __syncthreads();
    v = red[0] + red[1] + red[2] + red[3];
    __syncthreads();
    return v;
}

// x1 = LN2( LN1(av + x)*g1+b1 + x ); writes x1 (f32) and bf16(x1). D=1024, 4/thread.
__global__ __launch_bounds__(256) void ln_double(const float* __restrict__ av,
                                                 const float* __restrict__ xin,
                                                 const float* __restrict__ g1, const float* __restrict__ b1,
                                                 const float* __restrict__ g2, const float* __restrict__ b2,
                                                 float* __restrict__ xout,
                                                 unsigned short* __restrict__ xbf, int D) {
    __shared__ float red[4];
    const int tid = threadIdx.x;
    const size_t base = (size_t)blockIdx.x * D + tid * 4;
    const float4 a4 = *(const float4*)(av + base);
    const float4 x4 = *(const float4*)(xin + base);
    float x[4] = {x4.x, x4.y, x4.z, x4.w};
    float t[4] = {a4.x + x[0], a4.y + x[1], a4.z + x[2], a4.w + x[3]};
    const float invD = 1.0f / D;

    float m = block_sum(t[0] + t[1] + t[2] + t[3], red, tid) * invD;
    float q = 0.f;
#pragma unroll
    for (int j = 0; j < 4; ++j) q += (t[j] - m) * (t[j] - m);
    q = block_sum(q, red, tid) * invD;
    float rs = rsqrtf(q + 1e-5f);

    float u[4];
#pragma unroll
    for (int j = 0; j < 4; ++j) {
        const int idx = tid * 4 + j;
        u[j] = (t[j] - m) * rs * g1[idx] + b1[idx] + x[j];
    }
    float m2 = block_sum(u[0] + u[1] + u[2] + u[3], red, tid) * invD;
    float q2 = 0.f;
#pragma unroll
    for (int j = 0; j < 4; ++j) q2 += (u[j] - m2) * (u[j] - m2);
    q2 = block_sum(q2, red, tid) * invD;
    float rs2 = rsqrtf(q2 + 1e-5f);

    float4 o4;
    unsigned short ob[4];
#pragma unroll
    for (int j = 0; j < 4; ++j) {
        const int idx = tid * 4 + j;
        float o = (u[j] - m2) * rs2 * g2[idx] + b2[idx];
        ((float*)&o4)[j] = o;
        ob[j] = f2bf(o);
    }
    *(float4*)(xout + base) = o4;
    *(uint2*)(xbf + base) = *(uint2*)ob;
}

// out = LN(a + b)*g + bb  (final LN to d_out)
__global__ __launch_bounds__(256) void ln_single(const float* __restrict__ a,
                                                 const float* __restrict__ b_,
                                                 const float* __restrict__ g, const float* __restrict__ bb,
                                                 float* __restrict__ out, int D) {
    __shared__ float red[4];
    const int tid = threadIdx.x;
    const size_t base = (size_t)blockIdx.x * D + tid * 4;
    const float4 a4 = *(const float4*)(a + base);
    const float4 x4 = *(const float4*)(b_ + base);
    float t[4] = {a4.x + x4.x, a4.y + x4.y, a4.z + x4.z, a4.w + x4.w};
    const float invD = 1.0f / D;
    float m = block_sum(t[0] + t[1] + t[2] + t[3], red, tid) * invD;
    float q = 0.f;
#pragma unroll
    for (int j = 0; j < 4; ++j) q += (t[j] - m) * (t[j] - m);
    q = block_sum(q, red, tid) * invD;
    float rs = rsqrtf(q + 1e-5f);
    float4 o4;
#pragma unroll
    for (int j = 0; j < 4; ++j) {
        const int idx = tid * 4 + j;
        ((float*)&o4)[j] = (t[j] - m) * rs * g[idx] + bb[idx];
    }
    *(float4*)(out + base) = o4;
}

// ---------------------------------------------------------------------------
extern "C" void kernel_launch(void* const* d_in, const int* in_sizes, int n_in,
                              void* d_out, int out_size, void* d_ws, size_t ws_size,
                              hipStream_t stream) {
    (void)in_sizes; (void)n_in; (void)out_size; (void)ws_size;
    constexpr int B = 4, S = 2048, T = 2048, D = 1024;
    constexpr int M = B * S;  // 8192
    constexpr long MD = (long)M * D;
    constexpr long ST = (long)S * T;
    constexpr long DD = (long)D * D;

    const float* x = (const float*)d_in[0];
    const float* y = (const float*)d_in[1];
    const float* w_in[8] = {(const float*)d_in[2],  (const float*)d_in[4],  (const float*)d_in[6],
                            (const float*)d_in[10], (const float*)d_in[12], (const float*)d_in[14],
                            (const float*)d_in[18], (const float*)d_in[20]};
    const float* bq_m = (const float*)d_in[3];
    const float* bk_m = (const float*)d_in[5];
    const float* bv_m = (const float*)d_in[7];
    const float* g_m = (const float*)d_in[8];
    const float* b_m = (const float*)d_in[9];
    const float* bq_c = (const float*)d_in[11];
    const float* bk_c = (const float*)d_in[13];
    const float* bv_c = (const float*)d_in[15];
    const float* g_c = (const float*)d_in[16];
    const float* b_c = (const float*)d_in[17];
    const float* f0_b = (const float*)d_in[19];
    const float* f1_b = (const float*)d_in[21];
    const float* g_d = (const float*)d_in[22];
    const float* b_d = (const float*)d_in[23];
    float* dout = (float*)d_out;

    // workspace carve
    char* p = (char*)d_ws;
    auto carve = [&](size_t bytes) { void* r = p; p += (bytes + 255) & ~(size_t)255; return r; };
    float* xcur = (float*)carve(MD * 4);
    unsigned short* wT = (unsigned short*)carve((size_t)8 * DD * 2);
    unsigned short* abf = (unsigned short*)carve(MD * 2);   // abf, ybf adjacent (stride MD)
    unsigned short* ybf = (unsigned short*)carve(MD * 2);
    unsigned short* Qb = (unsigned short*)carve(MD * 2);    // Qb, Kb adjacent (stride MD)
    unsigned short* Kb = (unsigned short*)carve(MD * 2);
    unsigned short* Vt = (unsigned short*)carve(MD * 2);
    unsigned short* scores = (unsigned short*)carve((size_t)B * ST * 2);
    float* tmp = (float*)carve(MD * 4);
    float* bqk_m = (float*)carve(2 * D * 4);  // [bq_m ; bk_m]
    float* bqk_c = (float*)carve(2 * D * 4);  // [bq_c ; bk_c]

    const dim3 blk256(256);
    const dim3 tb(32, 8);

    // setup: weight transposes, input casts, adjacent bias staging
    for (int w = 0; w < 8; ++w)
        transpose_cast_w<<<dim3(32, 32), tb, 0, stream>>>(w_in[w], wT + (size_t)w * DD, D, D);
    cast_f32_bf16<<<dim3(M * D / 4 / 256), blk256, 0, stream>>>(x, abf, M * D / 4);
    cast_f32_bf16<<<dim3(M * D / 4 / 256), blk256, 0, stream>>>(y, ybf, M * D / 4);
    hipMemcpyAsync(bqk_m, bq_m, D * 4, hipMemcpyDeviceToDevice, stream);
    hipMemcpyAsync(bqk_m + D, bk_m, D * 4, hipMemcpyDeviceToDevice, stream);
    hipMemcpyAsync(bqk_c, bq_c, D * 4, hipMemcpyDeviceToDevice, stream);
    hipMemcpyAsync(bqk_c + D, bk_c, D * 4, hipMemcpyDeviceToDevice, stream);

    unsigned short* wqm = wT + 0 * DD;
    unsigned short* wvm = wT + 2 * DD;
    unsigned short* wqc = wT + 3 * DD;
    unsigned short* wvc = wT + 5 * DD;
    unsigned short* wf0 = wT + 6 * DD;
    unsigned short* wf1 = wT + 7 * DD;

    const dim3 gQK(M / 128, D / 128, 2);     // 64 x 8 x 2 = 1024 blocks
    const dim3 gVt(D / 128, T / 128, B);     // 8 x 16 x 4 = 512
    const dim3 gScores(S / 128, T / 128, B); // 16 x 16 x 4 = 1024
    const dim3 gPV(S / 128, D / 128, B);     // 16 x 8 x 4 = 512
    const dim3 gFFN(M / 128, D / 128, 1);    // 64 x 8 = 512

    // ===== stage 1: self attention =====
    gemm128<1, false, false><<<gQK, blk256, 0, stream>>>(abf, wqm, bqk_m, nullptr, Qb, D, D, D, D, 1.f, 0, DD, MD, D);
    gemm128<2, false, false><<<gVt, blk256, 0, stream>>>(wvm, abf, bv_m, nullptr, Vt, T, D, D, D, 1.f, 0, (long)S * D, (long)D * T, 0);
    gemm128<0, false, false><<<gScores, blk256, 0, stream>>>(Qb, Kb, nullptr, nullptr, scores, T, D, D, D, 0.125f, (long)S * D, (long)T * D, ST, 0);
    softmax_rows<<<dim3(B * S), blk256, 0, stream>>>(scores, T);
    gemm128<0, false, true><<<gPV, blk256, 0, stream>>>(scores, Vt, nullptr, tmp, nullptr, D, T, T, T, 1.f, ST, (long)T * D, (long)S * D, 0);
    ln_double<<<dim3(M), blk256, 0, stream>>>(tmp, x, g_m, b_m, g_d, b_d, xcur, abf, D);

    // ===== stage 2: cross attention =====
    gemm128<1, false, false><<<gQK, blk256, 0, stream>>>(abf, wqc, bqk_c, nullptr, Qb, D, D, D, D, 1.f, MD, DD, MD, D);
    gemm128<2, false, false><<<gVt, blk256, 0, stream>>>(wvc, ybf, bv_c, nullptr, Vt, T, D, D, D, 1.f, 0, (long)S * D, (long)D * T, 0);
    gemm128<0, false, false><<<gScores, blk256, 0, stream>>>(Qb, Kb, nullptr, nullptr, scores, T, D, D, D, 0.125f, (long)S * D, (long)T * D, ST, 0);
    softmax_rows<<<dim3(B * S), blk256, 0, stream>>>(scores, T);
    gemm128<0, false, true><<<gPV, blk256, 0, stream>>>(scores, Vt, nullptr, tmp, nullptr, D, T, T, T, 1.f, ST, (long)T * D, (long)S * D, 0);
    ln_double<<<dim3(M), blk256, 0, stream>>>(tmp, xcur, g_c, b_c, g_d, b_d, xcur, abf, D);

    // ===== stage 3: FFN =====
    gemm128<1, true, false><<<gFFN, blk256, 0, stream>>>(abf, wf0, f0_b, nullptr, Qb, D, D, D, D, 1.f, 0, 0, 0, 0);
    gemm128<1, true, true><<<gFFN, blk256, 0, stream>>>(Qb, wf1, f1_b, tmp, nullptr, D, D, D, D, 1.f, 0, 0, 0, 0);
    ln_single<<<dim3(M), blk256, 0, stream>>>(tmp, xcur, g_d, b_d, dout, D);
}

// Round 8
// 462.170 us; speedup vs baseline: 1.1327x; 1.1327x over previous
//
#include <hip/hip_runtime.h>

#define DEV __device__ __forceinline__

typedef __attribute__((ext_vector_type(8))) short bf16x8;
typedef __attribute__((ext_vector_type(4))) float f32x4;

DEV float bf2f(unsigned short u) { return __uint_as_float(((unsigned int)u) << 16); }
DEV unsigned short f2bf(float f) {
    unsigned int x = __float_as_uint(f);
    return (unsigned short)((x + 0x7fffu + ((x >> 16) & 1u)) >> 16);
}
DEV float gelu_exact(float x) { return 0.5f * x * (1.0f + erff(x * 0.7071067811865475f)); }

DEV void gload16(const void* g, void* l) {
    __builtin_amdgcn_global_load_lds((const __attribute__((address_space(1))) void*)g,
                                     (__attribute__((address_space(3))) void*)l, 16, 0, 0);
}

template <int OFF>
DEV bf16x8 ds_read128(unsigned addr) {
    bf16x8 r;
    asm volatile("ds_read_b128 %0, %1 offset:%2" : "=v"(r) : "v"(addr), "i"(OFF));
    return r;
}

// ---------------------------------------------------------------------------
// batched transpose + cast: w[z] f32 [R][C] -> wT[z] bf16 [C][R]
struct WPtrs { const float* p[8]; };

__global__ __launch_bounds__(256) void transpose_cast_w8(WPtrs wp,
                                                         unsigned short* __restrict__ out,
                                                         int R, int C) {
    const float* in = wp.p[blockIdx.z];
    out += (size_t)blockIdx.z * R * C;
    __shared__ float tile[32][33];
    int c0 = blockIdx.x * 32, r0 = blockIdx.y * 32;
    int tx = threadIdx.x, ty = threadIdx.y;  // 32 x 8
#pragma unroll
    for (int i = 0; i < 32; i += 8)
        tile[ty + i][tx] = in[(size_t)(r0 + ty + i) * C + (c0 + tx)];
    __syncthreads();
#pragma unroll
    for (int i = 0; i < 32; i += 8)
        out[(size_t)(c0 + ty + i) * R + (r0 + tx)] = f2bf(tile[tx][ty + i]);
}

// f32 -> bf16 cast, 4 elems/thread
__global__ __launch_bounds__(256) void cast_f32_bf16(const float* __restrict__ in,
                                                     unsigned short* __restrict__ out, int n4) {
    int i = blockIdx.x * 256 + threadIdx.x;
    if (i >= n4) return;
    float4 v = ((const float4*)in)[i];
    unsigned short o[4] = {f2bf(v.x), f2bf(v.y), f2bf(v.z), f2bf(v.w)};
    *(uint2*)(out + (size_t)i * 4) = *(uint2*)o;
}

// ---------------------------------------------------------------------------
// 128x128 bf16 GEMM (R6 structure: best measured), BK=64, 4 waves, 64 KiB LDS,
// 2 blocks/CU. C = act( scale * (A @ BT^T) + bias ), A:[M][K], BT:[N][K] bf16.
//   Swizzle: 16B-chunk XOR c' = (c&~7)|((c&7)^(row&7)) on global src + ds_read.
//   XCD-aware block remap. BIAS_MODE: 0 none, 1 per-col, 2 per-row.
//   biasB: if non-null and z==1, overrides bias (fused Q/K projection).

template <int H>
DEV void mfma16q(const bf16x8 (&a)[2][2], const bf16x8 (&b)[4][2], f32x4 (&acc)[4][4]) {
#pragma unroll
    for (int ks = 0; ks < 2; ++ks)
#pragma unroll
        for (int n = 0; n < 4; ++n) {
            acc[2 * H][n]     = __builtin_amdgcn_mfma_f32_16x16x32_bf16(a[0][ks], b[n][ks], acc[2 * H][n], 0, 0, 0);
            acc[2 * H + 1][n] = __builtin_amdgcn_mfma_f32_16x16x32_bf16(a[1][ks], b[n][ks], acc[2 * H + 1][n], 0, 0, 0);
        }
}

template <int BIAS_MODE, bool GELU_ACT, bool OUT_F32>
__global__ __launch_bounds__(256, 2) void gemm128(const unsigned short* __restrict__ A,
                                                  const unsigned short* __restrict__ BT,
                                                  const float* __restrict__ bias,
                                                  const float* __restrict__ biasB,
                                                  float* __restrict__ Cf,
                                                  unsigned short* __restrict__ Cb,
                                                  int N, int K, int lda, int ldb, float scale,
                                                  long sA, long sB, long sC) {
    // XCD-aware bijective block remap (nwg % 8 == 0 for all our grids)
    const int gx = gridDim.x, gy = gridDim.y;
    int f = blockIdx.x + gx * (blockIdx.y + gy * blockIdx.z);
    const int nwg = gx * gy * gridDim.z;
    f = (f & 7) * (nwg >> 3) + (f >> 3);
    const int bz = f / (gx * gy);
    const int rem = f - bz * gx * gy;
    const int by = rem / gx;
    const int bx = rem - by * gx;

    A += (long)bz * sA;
    BT += (long)bz * sB;
    if (BIAS_MODE == 1 && biasB != nullptr && bz == 1) bias = biasB;

    const int tid = threadIdx.x;
    const int lane = tid & 63;
    const int wave = tid >> 6;          // 0..3
    const int wr = wave >> 1;           // 0..1 : 64-row strip
    const int wc = wave & 1;            // 0..1 : 64-col strip
    const int llo = lane & 15, lhi = lane >> 4;
    const int bm = bx * 128, bn = by * 128;

    __shared__ unsigned short lds[2][2][128 * 64];  // [buf][A,B] = 64 KiB

    // ds_read swizzled k-offsets
    const int xk0 = (0 + lhi) ^ (llo & 7);
    const int xk1 = (4 + lhi) ^ (llo & 7);

    const unsigned base0 = (unsigned)(size_t)&lds[0][0][0];
    const unsigned aA0 = base0 + (unsigned)(wr * 64 + llo) * 128u + xk0 * 16;
    const unsigned aA1 = base0 + (unsigned)(wr * 64 + llo) * 128u + xk1 * 16;
    const unsigned aB0 = base0 + (unsigned)(wc * 64 + llo) * 128u + xk0 * 16;
    const unsigned aB1 = base0 + (unsigned)(wc * 64 + llo) * 128u + xk1 * 16;

    // staging: 4 chunks/thread per [128][64] half; chunk d = L*256 + tid;
    // source col chunk XOR-swizzled, LDS dest linear.
    int srow[4], sq[4];
#pragma unroll
    for (int L = 0; L < 4; ++L) {
        const int d = L * 256 + tid;
        srow[L] = d >> 3;
        sq[L] = (d & 7) ^ (srow[L] & 7);
    }
    const unsigned short* gA = A + (size_t)bm * lda;
    const unsigned short* gB = BT + (size_t)bn * ldb;

#define SA(kt, BUF)                                                                     \
    {                                                                                   \
        _Pragma("unroll") for (int L = 0; L < 4; ++L)                                   \
            gload16(gA + (size_t)srow[L] * lda + (kt) + sq[L] * 8,                      \
                    &lds[BUF][0][(L * 256 + wave * 64) * 8]);                           \
    }
#define SB(kt, BUF)                                                                     \
    {                                                                                   \
        _Pragma("unroll") for (int L = 0; L < 4; ++L)                                   \
            gload16(gB + (size_t)srow[L] * ldb + (kt) + sq[L] * 8,                      \
                    &lds[BUF][1][(L * 256 + wave * 64) * 8]);                           \
    }

    f32x4 acc[4][4] = {};
    bf16x8 b[4][2];

#define PH(H, BUF, LOADB, STG, TAIL)                                         \
    {                                                                        \
        STG;                                                                 \
        bf16x8 afr[2][2];                                                    \
        afr[0][0] = ds_read128<(BUF)*32768 + (H)*4096 + 0>(aA0);             \
        afr[0][1] = ds_read128<(BUF)*32768 + (H)*4096 + 0>(aA1);             \
        afr[1][0] = ds_read128<(BUF)*32768 + (H)*4096 + 2048>(aA0);          \
        afr[1][1] = ds_read128<(BUF)*32768 + (H)*4096 + 2048>(aA1);          \
        if (LOADB) {                                                         \
            b[0][0] = ds_read128<(BUF)*32768 + 16384 + 0>(aB0);              \
            b[0][1] = ds_read128<(BUF)*32768 + 16384 + 0>(aB1);              \
            b[1][0] = ds_read128<(BUF)*32768 + 16384 + 2048>(aB0);           \
            b[1][1] = ds_read128<(BUF)*32768 + 16384 + 2048>(aB1);           \
            b[2][0] = ds_read128<(BUF)*32768 + 16384 + 4096>(aB0);           \
            b[2][1] = ds_read128<(BUF)*32768 + 16384 + 4096>(aB1);           \
            b[3][0] = ds_read128<(BUF)*32768 + 16384 + 6144>(aB0);           \
            b[3][1] = ds_read128<(BUF)*32768 + 16384 + 6144>(aB1);           \
        }                                                                    \
        __builtin_amdgcn_s_barrier();                                        \
        asm volatile("s_waitcnt lgkmcnt(0)" :::);                            \
        __builtin_amdgcn_sched_barrier(0);                                   \
        __builtin_amdgcn_s_setprio(1);                                       \
        mfma16q<H>(afr, b, acc);                                             \
        __builtin_amdgcn_s_setprio(0);                                       \
        TAIL;                                                                \
        __builtin_amdgcn_s_barrier();                                        \
    }

#define VM0 asm volatile("s_waitcnt vmcnt(0)" :::)
#define NOP ((void)0)

    const int nt = K >> 6;  // K-tiles of 64 (even: 16 or 32 here)

    // prologue: tile0 -> buf0
    SA(0, 0);
    SB(0, 0);
    VM0;
    __builtin_amdgcn_s_barrier();

    int kt = 0;
    for (int t = 0; t < nt; t += 2) {
        const bool st0 = (t + 1 < nt);
        const bool st1 = (t + 2 < nt);
        PH(0, 0, true,  if (st0) { SA(kt + 64, 1); SB(kt + 64, 1); }, NOP);
        PH(1, 0, false, NOP, VM0);
        PH(0, 1, true,  if (st1) { SA(kt + 128, 0); SB(kt + 128, 0); }, NOP);
        PH(1, 1, false, NOP, VM0);
        kt += 128;
    }
#undef PH
#undef SA
#undef SB
#undef VM0
#undef NOP

    // epilogue: C/D frag layout col = llo, row = lhi*4 + j
#pragma unroll
    for (int m = 0; m < 4; ++m) {
#pragma unroll
        for (int n = 0; n < 4; ++n) {
            const int col = bn + wc * 64 + n * 16 + llo;
            float bcol = 0.f;
            if constexpr (BIAS_MODE == 1) bcol = bias[col];
#pragma unroll
            for (int j = 0; j < 4; ++j) {
                const int row = bm + wr * 64 + m * 16 + lhi * 4 + j;
                float v = acc[m][n][j] * scale + bcol;
                if constexpr (BIAS_MODE == 2) v += bias[row];
                if constexpr (GELU_ACT) v = gelu_exact(v);
                const size_t idx = (size_t)bz * (size_t)sC + (size_t)row * N + col;
                if constexpr (OUT_F32) Cf[idx] = v;
                else Cb[idx] = f2bf(v);
            }
        }
    }
}

// ---------------------------------------------------------------------------
// row softmax in place on bf16 scores, one block per row, T = 8*blockDim.x
__global__ __launch_bounds__(256) void softmax_rows(unsigned short* __restrict__ s, int T) {
    __shared__ float red[4];
    unsigned short* p = s + (size_t)blockIdx.x * T;
    const int tid = threadIdx.x;

    uint4 raw = *(const uint4*)(p + tid * 8);
    const unsigned short* u = (const unsigned short*)&raw;
    float v[8];
#pragma unroll
    for (int j = 0; j < 8; ++j) v[j] = bf2f(u[j]);

    float mx = -3.4e38f;
#pragma unroll
    for (int j = 0; j < 8; ++j) mx = fmaxf(mx, v[j]);
#pragma unroll
    for (int o = 32; o; o >>= 1) mx = fmaxf(mx, __shfl_xor(mx, o));
    if ((tid & 63) == 0) red[tid >> 6] = mx;
    __syncthreads();
    mx = fmaxf(fmaxf(red[0], red[1]), fmaxf(red[2], red[3]));
    __syncthreads();

    float sum = 0.f;
#pragma unroll
    for (int j = 0; j < 8; ++j) {
        v[j] = expf(v[j] - mx);
        sum += v[j];
    }
#pragma unroll
    for (int o = 32; o; o >>= 1) sum += __shfl_xor(sum, o);
    if ((tid & 63) == 0) red[tid >> 6] = sum;
    __syncthreads();
    sum = red[0] + red[1] + red[2] + red[3];
    const float inv = 1.0f / sum;

    unsigned short o8[8];
#pragma unroll
    for (int j = 0; j < 8; ++j) o8[j] = f2bf(v[j] * inv);
    *(uint4*)(p + tid * 8) = *(uint4*)o8;
}

// ---------------------------------------------------------------------------
DEV float block_sum(float v, float* red, int tid) {
#pragma unroll
    for (int o = 32; o; o >>= 1) v += __shfl_xor(v, o);
    if ((tid & 63) == 0) red[tid >> 6] = v;
    __syncthreads();
    v = red[0] + red[1] + red[2] + red[3];
    __syncthreads();
    return v;
}

// x1 = LN2( LN1(av + x)*g1+b1 + x ); av is bf16. Writes x1 f32 + bf16.
__global__ __launch_bounds__(256) void ln_double(const unsigned short* __restrict__ av,
                                                 const float* __restrict__ xin,
                                                 const float* __restrict__ g1, const float* __restrict__ b1,
                                                 const float* __restrict__ g2, const float* __restrict__ b2,
                                                 float* __restrict__ xout,
                                                 unsigned short* __restrict__ xbf, int D) {
    __shared__ float red[4];
    const int tid = threadIdx.x;
    const size_t base = (size_t)blockIdx.x * D + tid * 4;
    uint2 a2 = *(const uint2*)(av + base);
    const unsigned short* au = (const unsigned short*)&a2;
    const float4 x4 = *(const float4*)(xin + base);
    float x[4] = {x4.x, x4.y, x4.z, x4.w};
    float t[4];
#pragma unroll
    for (int j = 0; j < 4; ++j) t[j] = bf2f(au[j]) + x[j];
    const float invD = 1.0f / D;

    float m = block_sum(t[0] + t[1] + t[2] + t[3], red, tid) * invD;
    float q = 0.f;
#pragma unroll
    for (int j = 0; j < 4; ++j) q += (t[j] - m) * (t[j] - m);
    q = block_sum(q, red, tid) * invD;
    float rs = rsqrtf(q + 1e-5f);

    float u[4];
#pragma unroll
    for (int j = 0; j < 4; ++j) {
        const int idx = tid * 4 + j;
        u[j] = (t[j] - m) * rs * g1[idx] + b1[idx] + x[j];
    }
    float m2 = block_sum(u[0] + u[1] + u[2] + u[3], red, tid) * invD;
    float q2 = 0.f;
#pragma unroll
    for (int j = 0; j < 4; ++j) q2 += (u[j] - m2) * (u[j] - m2);
    q2 = block_sum(q2, red, tid) * invD;
    float rs2 = rsqrtf(q2 + 1e-5f);

    float4 o4;
    unsigned short ob[4];
#pragma unroll
    for (int j = 0; j < 4; ++j) {
        const int idx = tid * 4 + j;
        float o = (u[j] - m2) * rs2 * g2[idx] + b2[idx];
        ((float*)&o4)[j] = o;
        ob[j] = f2bf(o);
    }
    *(float4*)(xout + base) = o4;
    *(uint2*)(xbf + base) = *(uint2*)ob;
}

// out = LN(a + b)*g + bb, a is bf16 (final LN to d_out)
__global__ __launch_bounds__(256) void ln_single(const unsigned short* __restrict__ a,
                                                 const float* __restrict__ b_,
                                                 const float* __restrict__ g, const float* __restrict__ bb,
                                                 float* __restrict__ out, int D) {
    __shared__ float red[4];
    const int tid = threadIdx.x;
    const size_t base = (size_t)blockIdx.x * D + tid * 4;
    uint2 a2 = *(const uint2*)(a + base);
    const unsigned short* au = (const unsigned short*)&a2;
    const float4 x4 = *(const float4*)(b_ + base);
    float t[4] = {bf2f(au[0]) + x4.x, bf2f(au[1]) + x4.y, bf2f(au[2]) + x4.z, bf2f(au[3]) + x4.w};
    const float invD = 1.0f / D;
    float m = block_sum(t[0] + t[1] + t[2] + t[3], red, tid) * invD;
    float q = 0.f;
#pragma unroll
    for (int j = 0; j < 4; ++j) q += (t[j] - m) * (t[j] - m);
    q = block_sum(q, red, tid) * invD;
    float rs = rsqrtf(q + 1e-5f);
    float4 o4;
#pragma unroll
    for (int j = 0; j < 4; ++j) {
        const int idx = tid * 4 + j;
        ((float*)&o4)[j] = (t[j] - m) * rs * g[idx] + bb[idx];
    }
    *(float4*)(out + base) = o4;
}

// ---------------------------------------------------------------------------
extern "C" void kernel_launch(void* const* d_in, const int* in_sizes, int n_in,
                              void* d_out, int out_size, void* d_ws, size_t ws_size,
                              hipStream_t stream) {
    (void)in_sizes; (void)n_in; (void)out_size; (void)ws_size;
    constexpr int B = 4, S = 2048, T = 2048, D = 1024;
    constexpr int M = B * S;  // 8192
    constexpr long MD = (long)M * D;
    constexpr long ST = (long)S * T;
    constexpr long DD = (long)D * D;

    const float* x = (const float*)d_in[0];
    const float* y = (const float*)d_in[1];
    WPtrs wp;
    wp.p[0] = (const float*)d_in[2];   // wq_m
    wp.p[1] = (const float*)d_in[4];   // wk_m
    wp.p[2] = (const float*)d_in[6];   // wv_m
    wp.p[3] = (const float*)d_in[10];  // wq_c
    wp.p[4] = (const float*)d_in[12];  // wk_c
    wp.p[5] = (const float*)d_in[14];  // wv_c
    wp.p[6] = (const float*)d_in[18];  // f0_w
    wp.p[7] = (const float*)d_in[20];  // f1_w
    const float* bq_m = (const float*)d_in[3];
    const float* bk_m = (const float*)d_in[5];
    const float* bv_m = (const float*)d_in[7];
    const float* g_m = (const float*)d_in[8];
    const float* b_m = (const float*)d_in[9];
    const float* bq_c = (const float*)d_in[11];
    const float* bk_c = (const float*)d_in[13];
    const float* bv_c = (const float*)d_in[15];
    const float* g_c = (const float*)d_in[16];
    const float* b_c = (const float*)d_in[17];
    const float* f0_b = (const float*)d_in[19];
    const float* f1_b = (const float*)d_in[21];
    const float* g_d = (const float*)d_in[22];
    const float* b_d = (const float*)d_in[23];
    float* dout = (float*)d_out;

    // workspace carve
    char* p = (char*)d_ws;
    auto carve = [&](size_t bytes) { void* r = p; p += (bytes + 255) & ~(size_t)255; return r; };
    float* xcur = (float*)carve(MD * 4);
    unsigned short* wT = (unsigned short*)carve((size_t)8 * DD * 2);
    unsigned short* abf = (unsigned short*)carve(MD * 2);   // abf, ybf adjacent (stride MD)
    unsigned short* ybf = (unsigned short*)carve(MD * 2);
    unsigned short* Qb = (unsigned short*)carve(MD * 2);    // Qb, Kb adjacent (stride MD)
    unsigned short* Kb = (unsigned short*)carve(MD * 2);
    unsigned short* Vt = (unsigned short*)carve(MD * 2);
    unsigned short* scores = (unsigned short*)carve((size_t)B * ST * 2);
    unsigned short* tmpb = (unsigned short*)carve(MD * 2);  // bf16 attn/FFN out

    const dim3 blk256(256);
    const dim3 tb(32, 8);

    // setup: batched weight transpose + input casts
    transpose_cast_w8<<<dim3(32, 32, 8), tb, 0, stream>>>(wp, wT, D, D);
    cast_f32_bf16<<<dim3(M * D / 4 / 256), blk256, 0, stream>>>(x, abf, M * D / 4);
    cast_f32_bf16<<<dim3(M * D / 4 / 256), blk256, 0, stream>>>(y, ybf, M * D / 4);

    unsigned short* wqm = wT + 0 * DD;
    unsigned short* wvm = wT + 2 * DD;
    unsigned short* wqc = wT + 3 * DD;
    unsigned short* wvc = wT + 5 * DD;
    unsigned short* wf0 = wT + 6 * DD;
    unsigned short* wf1 = wT + 7 * DD;

    const dim3 gQK(M / 128, D / 128, 2);     // 64 x 8 x 2 = 1024 blocks
    const dim3 gVt(D / 128, T / 128, B);     // 8 x 16 x 4 = 512
    const dim3 gScores(S / 128, T / 128, B); // 16 x 16 x 4 = 1024
    const dim3 gPV(S / 128, D / 128, B);     // 16 x 8 x 4 = 512
    const dim3 gFFN(M / 128, D / 128, 1);    // 64 x 8 = 512

    // ===== stage 1: self attention =====
    // fused Q/K: z=0 -> (abf, wqm, bq_m) -> Qb; z=1 -> (abf, wkm, bk_m) -> Kb
    gemm128<1, false, false><<<gQK, blk256, 0, stream>>>(abf, wqm, bq_m, bk_m, nullptr, Qb, D, D, D, D, 1.f, 0, DD, MD);
    gemm128<2, false, false><<<gVt, blk256, 0, stream>>>(wvm, abf, bv_m, nullptr, nullptr, Vt, T, D, D, D, 1.f, 0, (long)S * D, (long)D * T);
    gemm128<0, false, false><<<gScores, blk256, 0, stream>>>(Qb, Kb, nullptr, nullptr, nullptr, scores, T, D, D, D, 0.125f, (long)S * D, (long)T * D, ST);
    softmax_rows<<<dim3(B * S), blk256, 0, stream>>>(scores, T);
    gemm128<0, false, false><<<gPV, blk256, 0, stream>>>(scores, Vt, nullptr, nullptr, nullptr, tmpb, D, T, T, T, 1.f, ST, (long)T * D, (long)S * D);
    ln_double<<<dim3(M), blk256, 0, stream>>>(tmpb, x, g_m, b_m, g_d, b_d, xcur, abf, D);

    // ===== stage 2: cross attention =====
    // fused Q/K: z=0 -> (abf, wqc, bq_c); z=1 -> (ybf, wkc, bk_c)   (sA=MD)
    gemm128<1, false, false><<<gQK, blk256, 0, stream>>>(abf, wqc, bq_c, bk_c, nullptr, Qb, D, D, D, D, 1.f, MD, DD, MD);
    gemm128<2, false, false><<<gVt, blk256, 0, stream>>>(wvc, ybf, bv_c, nullptr, nullptr, Vt, T, D, D, D, 1.f, 0, (long)S * D, (long)D * T);
    gemm128<0, false, false><<<gScores, blk256, 0, stream>>>(Qb, Kb, nullptr, nullptr, nullptr, scores, T, D, D, D, 0.125f, (long)S * D, (long)T * D, ST);
    softmax_rows<<<dim3(B * S), blk256, 0, stream>>>(scores, T);
    gemm128<0, false, false><<<gPV, blk256, 0, stream>>>(scores, Vt, nullptr, nullptr, nullptr, tmpb, D, T, T, T, 1.f, ST, (long)T * D, (long)S * D);
    ln_double<<<dim3(M), blk256, 0, stream>>>(tmpb, xcur, g_c, b_c, g_d, b_d, xcur, abf, D);

    // ===== stage 3: FFN =====
    gemm128<1, true, false><<<gFFN, blk256, 0, stream>>>(abf, wf0, f0_b, nullptr, nullptr, Qb, D, D, D, D, 1.f, 0, 0, 0);
    gemm128<1, true, false><<<gFFN, blk256, 0, stream>>>(Qb, wf1, f1_b, nullptr, nullptr, tmpb, D, D, D, D, 1.f, 0, 0, 0);
    ln_single<<<dim3(M), blk256, 0, stream>>>(tmpb, xcur, g_d, b_d, dout, D);
}